// Round 12
// baseline (289.145 us; speedup 1.0000x reference)
//
#include <hip/hip_runtime.h>
#include <math.h>
#include <float.h>

constexpr int NE   = 64;     // experts
constexpr int ND   = 2048;   // hidden dim
constexpr int TOPK = 8;
constexpr int TOKS = 64;     // tokens per block (= lanes)
constexpr int NWV  = 16;     // waves per block
constexpr int G    = NE / NWV; // 4 experts per wave
constexpr int KCH  = 64;     // k-chunk staged in LDS (divides 384 and 256 panels)

// Numerics contract (DO NOT CHANGE — validated in round 11):
// h @ w.T emulating OpenBLAS sgemm fp32: K=2048 in kc panels
// {384,384,384,384,256,256}; per C-element per panel ONE accumulator,
// serial fp32 FMA with k strictly ascending; panel sums added to C in
// order (__fadd_rn). Then np ufuncs: l = fadd(fmul(raw, cs), cb), fp32,
// unfused. Rank on l32, ties -> lower index. Softmax values fp32.
__global__ __launch_bounds__(NWV * 64, 1)
void gate_kernel(const float* __restrict__ h, const float* __restrict__ w,
                 const float* __restrict__ cs, const float* __restrict__ cb,
                 float* __restrict__ out, int T)
{
    __shared__ float wbuf[NWV][G][KCH];  // 16 KB: per-wave w staging
    __shared__ float sl[NE * TOKS];      // 16 KB: l32 logits [e][t]
    __shared__ float pp[TOKS * NE];      // 16 KB: [t][e] swizzled unnorm probs
    __shared__ float pinv[TOKS];

    const int tid  = threadIdx.x;
    const int lane = tid & 63;
    const int wv   = __builtin_amdgcn_readfirstlane(tid >> 6);
    const int tok  = blockIdx.x * TOKS + lane;
    const int e0   = wv * G;

    // staging roles: lane -> (expert sub-row, 4-float segment)
    const int se = lane >> 4;          // 0..3
    const int sj = (lane & 15) * 4;    // 0..60

    float C[G];
#pragma unroll
    for (int g = 0; g < G; ++g) C[g] = 0.f;

    const float* hrow = h + (size_t)tok * ND;
    const float* wsrc = w + (size_t)(e0 + se) * ND + sj;

    int k = 0;
#pragma unroll 1
    for (int p = 0; p < 6; ++p) {
        const int kend = (p < 4) ? (p + 1) * 384 : (1536 + (p - 3) * 256);

        float a[G];
#pragma unroll
        for (int g = 0; g < G; ++g) a[g] = 0.f;

#pragma unroll 1
        for (; k < kend; k += KCH) {
            // ---- stage this wave's 4 expert rows [k, k+KCH) into LDS ----
            // (same-wave produce/consume: compiler inserts vmcnt/lgkmcnt,
            // no block barrier needed)
            const float4 wstage = *reinterpret_cast<const float4*>(wsrc + k);
            *reinterpret_cast<float4*>(&wbuf[wv][se][sj]) = wstage;

            // ---- serial FMA chains over the chunk, k ascending ----
#pragma unroll
            for (int s = 0; s < KCH / 8; ++s) {
                const int kk = s * 8;
                const float4 h0 = *reinterpret_cast<const float4*>(hrow + k + kk);
                const float4 h1 = *reinterpret_cast<const float4*>(hrow + k + kk + 4);

#pragma unroll
                for (int g = 0; g < G; ++g) {
                    // same-address broadcast reads: conflict-free
                    const float4 w0 = *reinterpret_cast<const float4*>(&wbuf[wv][g][kk]);
                    const float4 w1 = *reinterpret_cast<const float4*>(&wbuf[wv][g][kk + 4]);
                    float t0 = a[g];
                    t0 = __builtin_fmaf(h0.x, w0.x, t0);
                    t0 = __builtin_fmaf(h0.y, w0.y, t0);
                    t0 = __builtin_fmaf(h0.z, w0.z, t0);
                    t0 = __builtin_fmaf(h0.w, w0.w, t0);
                    t0 = __builtin_fmaf(h1.x, w1.x, t0);
                    t0 = __builtin_fmaf(h1.y, w1.y, t0);
                    t0 = __builtin_fmaf(h1.z, w1.z, t0);
                    t0 = __builtin_fmaf(h1.w, w1.w, t0);
                    a[g] = t0;
                }
            }
        }

        // panel result added to C in fp32, in order (first panel: 0 + a, exact)
#pragma unroll
        for (int g = 0; g < G; ++g) C[g] = __fadd_rn(C[g], a[g]);
    }

    // np ufuncs: mul then add, both rounded fp32, no fma contraction
#pragma unroll
    for (int g = 0; g < G; ++g) {
        const int e = e0 + g;
        sl[e * TOKS + lane] = __fadd_rn(__fmul_rn(C[g], cs[e]), cb[e]);
    }
    __syncthreads();

    float* const out_probs = out;                           // T*64
    float* const out_wts   = out + (size_t)T * NE;          // T*8
    float* const out_idx   = out + (size_t)T * (NE + TOPK); // T*8

    if (wv == 0) {
        float l[NE];
#pragma unroll
        for (int e = 0; e < NE; ++e) l[e] = sl[e * TOKS + lane];

        float m = l[0];
#pragma unroll
        for (int e = 1; e < NE; ++e) m = fmaxf(m, l[e]);

        float u[NE];
        float s = 0.f;
#pragma unroll
        for (int e = 0; e < NE; ++e) {
            u[e] = expf(l[e] - m);
            s += u[e];
        }
        const float inv = 1.f / s;
        pinv[lane] = inv;

        // stage unnormalized probs, XOR-swizzled (conflict-free)
#pragma unroll
        for (int e = 0; e < NE; ++e)
            pp[lane * NE + (e ^ (lane & 31))] = u[e];

        // top-8 on l32; strict > insertion, e ascending => ties keep lower index
        float kv[TOPK]; int iv[TOPK];
#pragma unroll
        for (int j = 0; j < TOPK; ++j) { kv[j] = -FLT_MAX; iv[j] = 0; }
#pragma unroll
        for (int e = 0; e < NE; ++e) {
            float v = l[e]; int ix = e;
#pragma unroll
            for (int j = 0; j < TOPK; ++j) {
                const bool gt = v > kv[j];
                const float nv = gt ? kv[j] : v;
                const int   ni = gt ? iv[j] : ix;
                kv[j] = gt ? v  : kv[j];
                iv[j] = gt ? ix : iv[j];
                v = nv; ix = ni;
            }
        }

        float ws0[TOPK];
#pragma unroll
        for (int j = 0; j < TOPK; ++j)
            ws0[j] = pp[lane * NE + (iv[j] ^ (lane & 31))] * inv;

        *reinterpret_cast<float4*>(out_wts + (size_t)tok * TOPK)
            = make_float4(ws0[0], ws0[1], ws0[2], ws0[3]);
        *reinterpret_cast<float4*>(out_wts + (size_t)tok * TOPK + 4)
            = make_float4(ws0[4], ws0[5], ws0[6], ws0[7]);
        *reinterpret_cast<float4*>(out_idx + (size_t)tok * TOPK)
            = make_float4((float)iv[0], (float)iv[1], (float)iv[2], (float)iv[3]);
        *reinterpret_cast<float4*>(out_idx + (size_t)tok * TOPK + 4)
            = make_float4((float)iv[4], (float)iv[5], (float)iv[6], (float)iv[7]);
    }
    __syncthreads();

    // cooperative coalesced probs store: 4096 floats / 1024 threads = 4 each
    {
        const size_t base = (size_t)blockIdx.x * TOKS * NE;
#pragma unroll
        for (int r = 0; r < (TOKS * NE) / (NWV * 64); ++r) {
            const int idx = r * (NWV * 64) + tid;
            const int t = idx >> 6, e = idx & 63;
            out_probs[base + idx] = pp[t * NE + (e ^ (t & 31))] * pinv[t];
        }
    }
}

extern "C" void kernel_launch(void* const* d_in, const int* in_sizes, int n_in,
                              void* d_out, int out_size, void* d_ws, size_t ws_size,
                              hipStream_t stream)
{
    const float* h  = (const float*)d_in[0];
    const float* w  = (const float*)d_in[1];
    const float* cs = (const float*)d_in[2];
    const float* cb = (const float*)d_in[3];
    float* outp = (float*)d_out;
    const int T = in_sizes[0] / ND;   // 16384 tokens

    dim3 grid(T / TOKS);              // 256 blocks
    dim3 block(NWV * 64);             // 1024 threads
    hipLaunchKernelGGL(gate_kernel, grid, block, 0, stream,
                       h, w, cs, cb, outp, T);
}

// Round 13
// 248.994 us; speedup vs baseline: 1.1613x; 1.1613x over previous
//
#include <hip/hip_runtime.h>
#include <math.h>
#include <float.h>

constexpr int NE   = 64;     // experts (= lanes per wave)
constexpr int ND   = 2048;   // hidden dim
constexpr int TOPK = 8;
constexpr int GT   = 4;      // tokens per wave (serial chains per thread)
constexpr int BLK  = 256;    // threads per block -> 4 waves -> 16 tokens/block

// Numerics contract (DO NOT CHANGE — validated in round 11):
// h @ w.T emulating OpenBLAS sgemm fp32: K=2048 in kc panels
// {384,384,384,384,256,256}; per C-element per panel ONE accumulator,
// serial fp32 FMA with k strictly ascending; panel sums added to C in
// order (__fadd_rn). Then np ufuncs: l = fadd(fmul(raw, cs), cb), fp32,
// unfused. Rank on l32, ties -> lower index. Softmax value outputs fp32
// (2% threshold; reduction order free there).
__global__ __launch_bounds__(BLK)
void gate_kernel(const float* __restrict__ h, const float* __restrict__ w,
                 const float* __restrict__ cs, const float* __restrict__ cb,
                 float* __restrict__ out, int T)
{
    const int tid  = threadIdx.x;
    const int lane = tid & 63;                      // lane = expert
    // global wave id -> first token of this wave (wave-uniform)
    const int wgl  = __builtin_amdgcn_readfirstlane(
                        blockIdx.x * (BLK / 64) + (tid >> 6));
    const int t0   = wgl * GT;

    const float* wrow = w + (size_t)lane * ND;      // per-lane expert row
    const float* hbase = h + (size_t)t0 * ND;       // wave-uniform -> s_load

    float C[GT];
#pragma unroll
    for (int g = 0; g < GT; ++g) C[g] = 0.f;

    int k = 0;
#pragma unroll 1
    for (int p = 0; p < 6; ++p) {
        const int kend = (p < 4) ? (p + 1) * 384 : (1536 + (p - 3) * 256);

        float a[GT];
#pragma unroll
        for (int g = 0; g < GT; ++g) a[g] = 0.f;

#pragma unroll 1
        for (; k < kend; k += 16) {
            // per-lane w segment [k, k+16): 4 x b128; L1-hot (16 KB window
            // shared by all waves on the CU; w is 512 KB, L2-resident)
            const float4 w0 = *reinterpret_cast<const float4*>(wrow + k);
            const float4 w1 = *reinterpret_cast<const float4*>(wrow + k + 4);
            const float4 w2 = *reinterpret_cast<const float4*>(wrow + k + 8);
            const float4 w3 = *reinterpret_cast<const float4*>(wrow + k + 12);

#pragma unroll
            for (int g = 0; g < GT; ++g) {
                // wave-uniform h addresses -> scalar loads (SGPR broadcast)
                const float* hp = hbase + (size_t)g * ND + k;
                const float4 h0 = *reinterpret_cast<const float4*>(hp);
                const float4 h1 = *reinterpret_cast<const float4*>(hp + 4);
                const float4 h2 = *reinterpret_cast<const float4*>(hp + 8);
                const float4 h3 = *reinterpret_cast<const float4*>(hp + 12);

                // serial fp32 FMA, k strictly ascending (contract)
                float t = a[g];
                t = __builtin_fmaf(h0.x, w0.x, t);
                t = __builtin_fmaf(h0.y, w0.y, t);
                t = __builtin_fmaf(h0.z, w0.z, t);
                t = __builtin_fmaf(h0.w, w0.w, t);
                t = __builtin_fmaf(h1.x, w1.x, t);
                t = __builtin_fmaf(h1.y, w1.y, t);
                t = __builtin_fmaf(h1.z, w1.z, t);
                t = __builtin_fmaf(h1.w, w1.w, t);
                t = __builtin_fmaf(h2.x, w2.x, t);
                t = __builtin_fmaf(h2.y, w2.y, t);
                t = __builtin_fmaf(h2.z, w2.z, t);
                t = __builtin_fmaf(h2.w, w2.w, t);
                t = __builtin_fmaf(h3.x, w3.x, t);
                t = __builtin_fmaf(h3.y, w3.y, t);
                t = __builtin_fmaf(h3.z, w3.z, t);
                t = __builtin_fmaf(h3.w, w3.w, t);
                a[g] = t;
            }
        }

        // panel sums added to C in order (first panel: 0 + a, exact)
#pragma unroll
        for (int g = 0; g < GT; ++g) C[g] = __fadd_rn(C[g], a[g]);
    }

    float* const out_probs = out;                           // T*64
    float* const out_wts   = out + (size_t)T * NE;          // T*8
    float* const out_idx   = out + (size_t)T * (NE + TOPK); // T*8

    const float csv = cs[lane];
    const float cbv = cb[lane];

#pragma unroll
    for (int g = 0; g < GT; ++g) {
        const int tok = t0 + g;
        // np ufuncs: mul then add, both rounded fp32, no fma contraction
        const float l = __fadd_rn(__fmul_rn(C[g], csv), cbv);

        // exact max via butterfly (order-free)
        float m = l;
#pragma unroll
        for (int d = 1; d < 64; d <<= 1) m = fmaxf(m, __shfl_xor(m, d));

        const float u = expf(l - m);
        float s = u;
#pragma unroll
        for (int d = 1; d < 64; d <<= 1) s += __shfl_xor(s, d);
        const float p = u * (1.f / s);

        out_probs[(size_t)tok * NE + lane] = p;   // coalesced 256B/wave

        // top-8 on l: repeated butterfly argmax, ties -> lower index
        float curv = l;
        float myw = 0.f; int myi = 0;
#pragma unroll
        for (int r = 0; r < TOPK; ++r) {
            float v = curv; int ix = lane;
#pragma unroll
            for (int d = 1; d < 64; d <<= 1) {
                const float ov = __shfl_xor(v, d);
                const int   oi = __shfl_xor(ix, d);
                const bool take = (ov > v) || (ov == v && oi < ix);
                v  = take ? ov : v;
                ix = take ? oi : ix;
            }
            const float pw = __shfl(p, ix);
            if (lane == r) { myw = pw; myi = ix; }
            if (lane == ix) curv = -FLT_MAX;
        }
        if (lane < TOPK) {
            out_wts[(size_t)tok * TOPK + lane] = myw;
            out_idx[(size_t)tok * TOPK + lane] = (float)myi;
        }
    }
}

extern "C" void kernel_launch(void* const* d_in, const int* in_sizes, int n_in,
                              void* d_out, int out_size, void* d_ws, size_t ws_size,
                              hipStream_t stream)
{
    const float* h  = (const float*)d_in[0];
    const float* w  = (const float*)d_in[1];
    const float* cs = (const float*)d_in[2];
    const float* cb = (const float*)d_in[3];
    float* outp = (float*)d_out;
    const int T = in_sizes[0] / ND;   // 16384 tokens

    const int tokens_per_block = (BLK / 64) * GT;   // 16
    dim3 grid(T / tokens_per_block);                // 1024 blocks
    dim3 block(BLK);
    hipLaunchKernelGGL(gate_kernel, grid, block, 0, stream,
                       h, w, cs, cb, outp, T);
}